// Round 1
// baseline (1251.740 us; speedup 1.0000x reference)
//
#include <hip/hip_runtime.h>

#define M_ROWS 100000
#define MPAD   100096          // 782 * 128
#define FW     512
#define INMSG  1024

typedef __attribute__((ext_vector_type(4))) float f32x4;
typedef __attribute__((ext_vector_type(8))) short bf16x8;

__device__ __forceinline__ unsigned short f2bf(float f) {
    unsigned u = __builtin_bit_cast(unsigned, f);
    u += 0x7fffu + ((u >> 16) & 1u);      // round-to-nearest-even
    return (unsigned short)(u >> 16);
}

__device__ __forceinline__ float selu_f(float x) {
    const float scale = 1.0507009873554805f;
    const float alpha = 1.6732632423543772f;
    return scale * (x > 0.0f ? x : alpha * expm1f(x));
}

// ---------------- weight convert: f32 -> bf16, vectorized ----------------
__global__ __launch_bounds__(256) void f32_to_bf16_k(
    const float* __restrict__ in, unsigned short* __restrict__ out, int n4)
{
    int i = blockIdx.x * 256 + threadIdx.x;
    if (i < n4) {
        f32x4 x = ((const f32x4*)in)[i];
        ushort4 o;
        o.x = f2bf(x[0]); o.y = f2bf(x[1]); o.z = f2bf(x[2]); o.w = f2bf(x[3]);
        ((ushort4*)out)[i] = o;
    }
}

// ------- fused edge-encoder + gather + concat + LayerNorm -> bf16 msg -------
// one block (256 thr) per row; thread t owns elements [4t, 4t+4)
__global__ __launch_bounds__(256) void build_msg_k(
    const float* __restrict__ v, const float* __restrict__ e_rel,
    const int* __restrict__ idx, const float* __restrict__ v_skip,
    const float* __restrict__ We, const float* __restrict__ be,
    const float* __restrict__ ln_g, const float* __restrict__ ln_b,
    unsigned short* __restrict__ msg)
{
    const int r = blockIdx.x;
    const int t = threadIdx.x;

    f32x4 val;
    if (t < 128) {                       // e_enc = -e * We[:,0] + be
        float e = e_rel[r];
        f32x4 we = ((const f32x4*)We)[t];
        f32x4 bb = ((const f32x4*)be)[t];
        val = (-e) * we + bb;
    } else if (t < 192) {                // gathered v row
        long vr = (long)idx[r] * 256;
        val = ((const f32x4*)(v + vr))[t - 128];
    } else {                             // v_skip row
        val = ((const f32x4*)(v_skip + (long)r * 256))[t - 192];
    }

    float s = val[0] + val[1] + val[2] + val[3];
    float q = val[0]*val[0] + val[1]*val[1] + val[2]*val[2] + val[3]*val[3];
    #pragma unroll
    for (int off = 32; off; off >>= 1) {
        s += __shfl_down(s, off, 64);
        q += __shfl_down(q, off, 64);
    }
    __shared__ float red[8];
    const int lane = t & 63, wv = t >> 6;
    if (lane == 0) { red[wv] = s; red[4 + wv] = q; }
    __syncthreads();
    float S  = red[0] + red[1] + red[2] + red[3];
    float Q  = red[4] + red[5] + red[6] + red[7];
    float mu = S * (1.0f / 1024.0f);
    float var = Q * (1.0f / 1024.0f) - mu * mu;
    float rs = rsqrtf(var + 1e-5f);

    f32x4 g = ((const f32x4*)ln_g)[t];
    f32x4 b = ((const f32x4*)ln_b)[t];
    ushort4 o;
    o.x = f2bf((val[0] - mu) * rs * g[0] + b[0]);
    o.y = f2bf((val[1] - mu) * rs * g[1] + b[1]);
    o.z = f2bf((val[2] - mu) * rs * g[2] + b[2]);
    o.w = f2bf((val[3] - mu) * rs * g[3] + b[3]);
    ((ushort4*)(msg + (long)r * INMSG))[t] = o;
}

// ---------------- m97-style bf16 MFMA GEMM + bias + SELU ----------------
// C[m][n] = sum_k A[m][k] * W[n][k];  A: [MPAD][K] bf16, W: [512][K] bf16
// 128x128 tile, BK=64, 4 waves in 2x2, each wave 64x64 (4x4 of 16x16x32)
template<int K, bool LAST>
__global__ __launch_bounds__(256) void gemm_selu_k(
    const unsigned short* __restrict__ A,
    const unsigned short* __restrict__ W,
    const float* __restrict__ bias,
    void* __restrict__ out, int M)
{
    __shared__ __align__(16) unsigned short ldsA[128][64];
    __shared__ __align__(16) unsigned short ldsB[128][64];

    const int tid  = threadIdx.x;
    const int lane = tid & 63;
    const int w    = tid >> 6;
    const int wr   = w >> 1, wc = w & 1;
    const long m0  = (long)blockIdx.x * 128;
    const int  n0  = blockIdx.y * 128;

    f32x4 acc[4][4] = {};

    const int lr = lane >> 3;          // row within this wave's 8-row chunk
    const int lc = (lane & 7) * 8;     // k-offset (shorts), 16B granules

    for (int k0 = 0; k0 < K; k0 += 64) {
        #pragma unroll
        for (int i = 0; i < 4; ++i) {
            const int rowoff = i * 32 + w * 8;
            const unsigned short* ag = A + (m0 + rowoff + lr) * K + k0 + lc;
            __builtin_amdgcn_global_load_lds(
                (const __attribute__((address_space(1))) unsigned int*)ag,
                (__attribute__((address_space(3))) unsigned int*)&ldsA[rowoff][0],
                16, 0, 0);
            const unsigned short* bg = W + (long)(n0 + rowoff + lr) * K + k0 + lc;
            __builtin_amdgcn_global_load_lds(
                (const __attribute__((address_space(1))) unsigned int*)bg,
                (__attribute__((address_space(3))) unsigned int*)&ldsB[rowoff][0],
                16, 0, 0);
        }
        __syncthreads();

        #pragma unroll
        for (int kk = 0; kk < 2; ++kk) {
            bf16x8 af[4], bfr[4];
            #pragma unroll
            for (int mf = 0; mf < 4; ++mf)
                af[mf] = *(const bf16x8*)&ldsA[wr*64 + mf*16 + (lane & 15)][kk*32 + (lane >> 4)*8];
            #pragma unroll
            for (int nf = 0; nf < 4; ++nf)
                bfr[nf] = *(const bf16x8*)&ldsB[wc*64 + nf*16 + (lane & 15)][kk*32 + (lane >> 4)*8];
            #pragma unroll
            for (int mf = 0; mf < 4; ++mf)
                #pragma unroll
                for (int nf = 0; nf < 4; ++nf)
                    acc[mf][nf] = __builtin_amdgcn_mfma_f32_16x16x32_bf16(
                        af[mf], bfr[nf], acc[mf][nf], 0, 0, 0);
        }
        __syncthreads();
    }

    // epilogue: bias + SELU + store (guard r < M)
    #pragma unroll
    for (int nf = 0; nf < 4; ++nf) {
        const int col = n0 + wc*64 + nf*16 + (lane & 15);
        const float bv = bias[col];
        #pragma unroll
        for (int mf = 0; mf < 4; ++mf) {
            const long row = m0 + wr*64 + mf*16 + ((lane >> 4) * 4);
            #pragma unroll
            for (int i = 0; i < 4; ++i) {
                const long r = row + i;
                if (r < M) {
                    float x = acc[mf][nf][i] + bv;
                    float sv = selu_f(x);
                    if (LAST) ((float*)out)[r * FW + col] = sv;
                    else      ((unsigned short*)out)[r * FW + col] = f2bf(sv);
                }
            }
        }
    }
}

extern "C" void kernel_launch(void* const* d_in, const int* in_sizes, int n_in,
                              void* d_out, int out_size, void* d_ws, size_t ws_size,
                              hipStream_t stream) {
    const float* v      = (const float*)d_in[0];
    const float* e_rel  = (const float*)d_in[1];
    const int*   idx    = (const int*)d_in[2];
    const float* v_skip = (const float*)d_in[3];
    const float* We     = (const float*)d_in[4];
    const float* be     = (const float*)d_in[5];
    const float* ln_g   = (const float*)d_in[6];
    const float* ln_b   = (const float*)d_in[7];
    const float* W0 = (const float*)d_in[8];  const float* b0 = (const float*)d_in[9];
    const float* W1 = (const float*)d_in[10]; const float* b1 = (const float*)d_in[11];
    const float* W2 = (const float*)d_in[12]; const float* b2 = (const float*)d_in[13];
    const float* W3 = (const float*)d_in[14]; const float* b3 = (const float*)d_in[15];

    char* ws = (char*)d_ws;
    const size_t MSG_BYTES = (size_t)MPAD * INMSG * 2;   // 204,996,608
    const size_t H_BYTES   = (size_t)MPAD * FW * 2;      // 102,498,304
    unsigned short* msg = (unsigned short*)ws;
    unsigned short* W0b = (unsigned short*)(ws + MSG_BYTES);
    unsigned short* W1b = W0b + 1024 * 512;
    unsigned short* W2b = W1b + 512 * 512;
    unsigned short* W3b = W2b + 512 * 512;
    unsigned short* h0  = (unsigned short*)d_out;        // d_out as bf16 scratch
    unsigned short* h1  = (unsigned short*)ws;           // msg dead after L0
    unsigned short* h2  = (unsigned short*)(ws + H_BYTES);

    f32_to_bf16_k<<<dim3(512), 256, 0, stream>>>(W0, W0b, 1024 * 512 / 4);
    f32_to_bf16_k<<<dim3(256), 256, 0, stream>>>(W1, W1b, 512 * 512 / 4);
    f32_to_bf16_k<<<dim3(256), 256, 0, stream>>>(W2, W2b, 512 * 512 / 4);
    f32_to_bf16_k<<<dim3(256), 256, 0, stream>>>(W3, W3b, 512 * 512 / 4);

    build_msg_k<<<dim3(M_ROWS), 256, 0, stream>>>(v, e_rel, idx, v_skip,
                                                  We, be, ln_g, ln_b, msg);

    dim3 ggrid(MPAD / 128, FW / 128);
    gemm_selu_k<1024, false><<<ggrid, 256, 0, stream>>>(msg, W0b, b0, h0, M_ROWS);
    gemm_selu_k<512,  false><<<ggrid, 256, 0, stream>>>(h0,  W1b, b1, h1, M_ROWS);
    gemm_selu_k<512,  false><<<ggrid, 256, 0, stream>>>(h1,  W2b, b2, h2, M_ROWS);
    gemm_selu_k<512,  true ><<<ggrid, 256, 0, stream>>>(h2,  W3b, b3, d_out, M_ROWS);
}

// Round 3
// 1211.897 us; speedup vs baseline: 1.0329x; 1.0329x over previous
//
#include <hip/hip_runtime.h>

#define M_ROWS 100000
#define MPAD   100096          // 782 * 128
#define FW     512
#define INMSG  1024

typedef __attribute__((ext_vector_type(4))) float f32x4;
typedef __attribute__((ext_vector_type(8))) short bf16x8;

__device__ __forceinline__ unsigned short f2bf(float f) {
    unsigned u = __builtin_bit_cast(unsigned, f);
    u += 0x7fffu + ((u >> 16) & 1u);      // round-to-nearest-even
    return (unsigned short)(u >> 16);
}

__device__ __forceinline__ float selu_f(float x) {
    const float scale = 1.0507009873554805f;
    const float alpha = 1.6732632423543772f;
    return scale * (x > 0.0f ? x : alpha * expm1f(x));
}

// ---------------- weight convert: f32 -> bf16, vectorized ----------------
__global__ __launch_bounds__(256) void f32_to_bf16_k(
    const float* __restrict__ in, unsigned short* __restrict__ out, int n4)
{
    int i = blockIdx.x * 256 + threadIdx.x;
    if (i < n4) {
        f32x4 x = ((const f32x4*)in)[i];
        ushort4 o;
        o.x = f2bf(x[0]); o.y = f2bf(x[1]); o.z = f2bf(x[2]); o.w = f2bf(x[3]);
        ((ushort4*)out)[i] = o;
    }
}

// ------- fused edge-encoder + gather + concat + LayerNorm -> bf16 msg -------
// one block (256 thr) per row; thread t owns elements [4t, 4t+4)
__global__ __launch_bounds__(256) void build_msg_k(
    const float* __restrict__ v, const float* __restrict__ e_rel,
    const int* __restrict__ idx, const float* __restrict__ v_skip,
    const float* __restrict__ We, const float* __restrict__ be,
    const float* __restrict__ ln_g, const float* __restrict__ ln_b,
    unsigned short* __restrict__ msg)
{
    const int r = blockIdx.x;
    const int t = threadIdx.x;

    f32x4 val;
    if (t < 128) {                       // e_enc = -e * We[:,0] + be
        float e = e_rel[r];
        f32x4 we = ((const f32x4*)We)[t];
        f32x4 bb = ((const f32x4*)be)[t];
        val = (-e) * we + bb;
    } else if (t < 192) {                // gathered v row
        long vr = (long)idx[r] * 256;
        val = ((const f32x4*)(v + vr))[t - 128];
    } else {                             // v_skip row
        val = ((const f32x4*)(v_skip + (long)r * 256))[t - 192];
    }

    float s = val[0] + val[1] + val[2] + val[3];
    float q = val[0]*val[0] + val[1]*val[1] + val[2]*val[2] + val[3]*val[3];
    #pragma unroll
    for (int off = 32; off; off >>= 1) {
        s += __shfl_down(s, off, 64);
        q += __shfl_down(q, off, 64);
    }
    __shared__ float red[8];
    const int lane = t & 63, wv = t >> 6;
    if (lane == 0) { red[wv] = s; red[4 + wv] = q; }
    __syncthreads();
    float S  = red[0] + red[1] + red[2] + red[3];
    float Q  = red[4] + red[5] + red[6] + red[7];
    float mu = S * (1.0f / 1024.0f);
    float var = Q * (1.0f / 1024.0f) - mu * mu;
    float rs = rsqrtf(var + 1e-5f);

    f32x4 g = ((const f32x4*)ln_g)[t];
    f32x4 b = ((const f32x4*)ln_b)[t];
    ushort4 o;
    o.x = f2bf((val[0] - mu) * rs * g[0] + b[0]);
    o.y = f2bf((val[1] - mu) * rs * g[1] + b[1]);
    o.z = f2bf((val[2] - mu) * rs * g[2] + b[2]);
    o.w = f2bf((val[3] - mu) * rs * g[3] + b[3]);
    ((ushort4*)(msg + (long)r * INMSG))[t] = o;
}

// ---------------- m97-style bf16 MFMA GEMM + bias + SELU ----------------
// C[m][n] = sum_k A[m][k] * W[n][k];  A: [MPAD][K] bf16, W: [512][K] bf16
// 128x128 tile, BK=64, 4 waves in 2x2, each wave 64x64 (4x4 of 16x16x32).
//
// LDS XOR-swizzle (T2, rule #21 both-sides): tile row = 64 shorts = 128 B
// = one full bank wrap -> naive fragment read is 16-way conflicted.
// LDS granule (row, g) holds GLOBAL granule g ^ (row&7):
//   - staging: global_load_lds writes linearly (lane -> row=base+lane>>3,
//     g=lane&7), so the lane's GLOBAL src granule is (lane&7)^(lane>>3).
//   - read: want global granule G=kk*4+hi at row r -> read g = G ^ (r&7).
// Post-swizzle each 16B bank slot is hit by exactly 2 lanes (rows r,r+8)
// -> 2-way = free (m136).
template<int K, bool LAST>
__global__ __launch_bounds__(256) void gemm_selu_k(
    const unsigned short* __restrict__ A,
    const unsigned short* __restrict__ W,
    const float* __restrict__ bias,
    void* __restrict__ out, int M)
{
    __shared__ __align__(16) unsigned short ldsA[128][64];
    __shared__ __align__(16) unsigned short ldsB[128][64];

    const int tid  = threadIdx.x;
    const int lane = tid & 63;
    const int w    = tid >> 6;
    const int wr   = w >> 1, wc = w & 1;
    const long m0  = (long)blockIdx.x * 128;
    const int  n0  = blockIdx.y * 128;

    f32x4 acc[4][4] = {};

    const int lr = lane >> 3;                      // row within 8-row chunk
    const int lc = ((lane & 7) ^ lr) * 8;          // PRE-SWIZZLED global granule
    const int l15 = lane & 15;
    const int hi  = lane >> 4;
    const int l7  = lane & 7;

    for (int k0 = 0; k0 < K; k0 += 64) {
        #pragma unroll
        for (int i = 0; i < 4; ++i) {
            const int rowoff = i * 32 + w * 8;     // multiple of 8 -> row&7 == lr
            const unsigned short* ag = A + (m0 + rowoff + lr) * K + k0 + lc;
            __builtin_amdgcn_global_load_lds(
                (const __attribute__((address_space(1))) unsigned int*)ag,
                (__attribute__((address_space(3))) unsigned int*)&ldsA[rowoff][0],
                16, 0, 0);
            const unsigned short* bg = W + (long)(n0 + rowoff + lr) * K + k0 + lc;
            __builtin_amdgcn_global_load_lds(
                (const __attribute__((address_space(1))) unsigned int*)bg,
                (__attribute__((address_space(3))) unsigned int*)&ldsB[rowoff][0],
                16, 0, 0);
        }
        __syncthreads();

        #pragma unroll
        for (int kk = 0; kk < 2; ++kk) {
            bf16x8 af[4], bfr[4];
            #pragma unroll
            for (int mf = 0; mf < 4; ++mf) {
                const int g = (kk * 4 + hi) ^ l7;  // swizzled read granule
                af[mf] = *(const bf16x8*)&ldsA[wr*64 + mf*16 + l15][g * 8];
            }
            #pragma unroll
            for (int nf = 0; nf < 4; ++nf) {
                const int g = (kk * 4 + hi) ^ l7;
                bfr[nf] = *(const bf16x8*)&ldsB[wc*64 + nf*16 + l15][g * 8];
            }
            #pragma unroll
            for (int mf = 0; mf < 4; ++mf)
                #pragma unroll
                for (int nf = 0; nf < 4; ++nf)
                    acc[mf][nf] = __builtin_amdgcn_mfma_f32_16x16x32_bf16(
                        af[mf], bfr[nf], acc[mf][nf], 0, 0, 0);
        }
        __syncthreads();
    }

    // epilogue: bias + SELU + store (guard r < M)
    #pragma unroll
    for (int nf = 0; nf < 4; ++nf) {
        const int col = n0 + wc*64 + nf*16 + l15;
        const float bv = bias[col];
        #pragma unroll
        for (int mf = 0; mf < 4; ++mf) {
            const long row = m0 + wr*64 + mf*16 + hi * 4;
            #pragma unroll
            for (int i = 0; i < 4; ++i) {
                const long r = row + i;
                if (r < M) {
                    float x = acc[mf][nf][i] + bv;
                    float sv = selu_f(x);
                    if (LAST) ((float*)out)[r * FW + col] = sv;
                    else      ((unsigned short*)out)[r * FW + col] = f2bf(sv);
                }
            }
        }
    }
}

extern "C" void kernel_launch(void* const* d_in, const int* in_sizes, int n_in,
                              void* d_out, int out_size, void* d_ws, size_t ws_size,
                              hipStream_t stream) {
    const float* v      = (const float*)d_in[0];
    const float* e_rel  = (const float*)d_in[1];
    const int*   idx    = (const int*)d_in[2];
    const float* v_skip = (const float*)d_in[3];
    const float* We     = (const float*)d_in[4];
    const float* be     = (const float*)d_in[5];
    const float* ln_g   = (const float*)d_in[6];
    const float* ln_b   = (const float*)d_in[7];
    const float* W0 = (const float*)d_in[8];  const float* b0 = (const float*)d_in[9];
    const float* W1 = (const float*)d_in[10]; const float* b1 = (const float*)d_in[11];
    const float* W2 = (const float*)d_in[12]; const float* b2 = (const float*)d_in[13];
    const float* W3 = (const float*)d_in[14]; const float* b3 = (const float*)d_in[15];

    char* ws = (char*)d_ws;
    const size_t MSG_BYTES = (size_t)MPAD * INMSG * 2;   // 204,996,608
    const size_t H_BYTES   = (size_t)MPAD * FW * 2;      // 102,498,304
    unsigned short* msg = (unsigned short*)ws;
    unsigned short* W0b = (unsigned short*)(ws + MSG_BYTES);
    unsigned short* W1b = W0b + 1024 * 512;
    unsigned short* W2b = W1b + 512 * 512;
    unsigned short* W3b = W2b + 512 * 512;
    unsigned short* h0  = (unsigned short*)d_out;        // d_out as bf16 scratch
    unsigned short* h1  = (unsigned short*)ws;           // msg dead after L0
    unsigned short* h2  = (unsigned short*)(ws + H_BYTES);

    f32_to_bf16_k<<<dim3(512), 256, 0, stream>>>(W0, W0b, 1024 * 512 / 4);
    f32_to_bf16_k<<<dim3(256), 256, 0, stream>>>(W1, W1b, 512 * 512 / 4);
    f32_to_bf16_k<<<dim3(256), 256, 0, stream>>>(W2, W2b, 512 * 512 / 4);
    f32_to_bf16_k<<<dim3(256), 256, 0, stream>>>(W3, W3b, 512 * 512 / 4);

    build_msg_k<<<dim3(M_ROWS), 256, 0, stream>>>(v, e_rel, idx, v_skip,
                                                  We, be, ln_g, ln_b, msg);

    dim3 ggrid(MPAD / 128, FW / 128);
    gemm_selu_k<1024, false><<<ggrid, 256, 0, stream>>>(msg, W0b, b0, h0, M_ROWS);
    gemm_selu_k<512,  false><<<ggrid, 256, 0, stream>>>(h0,  W1b, b1, h1, M_ROWS);
    gemm_selu_k<512,  false><<<ggrid, 256, 0, stream>>>(h1,  W2b, b2, h2, M_ROWS);
    gemm_selu_k<512,  true ><<<ggrid, 256, 0, stream>>>(h2,  W3b, b3, d_out, M_ROWS);
}